// Round 1
// baseline (37653.387 us; speedup 1.0000x reference)
//
#include <hip/hip_runtime.h>
#include <hip/hip_bf16.h>
#include <stdint.h>

#define T_LEN 16384
#define HDIM 512
#define G4 2048
#define CLAMP_MAXV 49688.0f

// workspace layout (bytes)
#define XG_OFF    0ull
#define HS_OFF    134217728ull   // 16384*2048*4
#define INTER_OFF 167772160ull   // + 16384*512*4
#define HREC_OFF  176160768ull   // + 16384*128*4
#define BSUM_OFF  176168960ull   // + 8192
#define WS_NEED   176177152ull

// ---------------------------------------------------------------------------
// init: zero the h-record (both parity buffers incl. tags), fold biases
// ---------------------------------------------------------------------------
__global__ __launch_bounds__(256) void init_k(uint64_t* __restrict__ hrec,
                                              const float* __restrict__ b_ih,
                                              const float* __restrict__ b_hh,
                                              float* __restrict__ bsum) {
    int i = blockIdx.x * 256 + threadIdx.x;   // grid 8x256 -> i in [0,2048)
    if (i < 1024) hrec[i] = 0ull;             // tag 0 == "h_{-1} ready", h = 0
    bsum[i] = b_ih[i] + b_hh[i];
}

// ---------------------------------------------------------------------------
// C[M,N] = A[M,K] @ B[N,K]^T + bias[N]   (both operands K-contiguous)
// 64x64 tile, 256 threads, 4x4 micro-tile, K-tile 16, LDS transposed + padded
// ---------------------------------------------------------------------------
__global__ __launch_bounds__(256) void gemm_abt(const float* __restrict__ A,
                                                const float* __restrict__ B,
                                                const float* __restrict__ bias,
                                                float* __restrict__ C,
                                                int N, int K) {
    __shared__ float As[16][68];
    __shared__ float Bs[16][68];
    const int tid = threadIdx.x;
    const int bm = blockIdx.x << 6, bn = blockIdx.y << 6;
    const int tx = tid & 15, ty = tid >> 4;
    const int lr = tid >> 2, lk = (tid & 3) << 2;
    float acc[4][4] = {};
    const float* Ap = A + (size_t)(bm + lr) * K + lk;
    const float* Bp = B + (size_t)(bn + lr) * K + lk;
    for (int kt = 0; kt < K; kt += 16) {
        float4 av = *(const float4*)(Ap + kt);
        float4 bv = *(const float4*)(Bp + kt);
        __syncthreads();
        As[lk + 0][lr] = av.x; As[lk + 1][lr] = av.y;
        As[lk + 2][lr] = av.z; As[lk + 3][lr] = av.w;
        Bs[lk + 0][lr] = bv.x; Bs[lk + 1][lr] = bv.y;
        Bs[lk + 2][lr] = bv.z; Bs[lk + 3][lr] = bv.w;
        __syncthreads();
#pragma unroll
        for (int kk = 0; kk < 16; ++kk) {
            float4 a4 = *(const float4*)&As[kk][ty << 2];
            float4 b4 = *(const float4*)&Bs[kk][tx << 2];
            acc[0][0] += a4.x * b4.x; acc[0][1] += a4.x * b4.y;
            acc[0][2] += a4.x * b4.z; acc[0][3] += a4.x * b4.w;
            acc[1][0] += a4.y * b4.x; acc[1][1] += a4.y * b4.y;
            acc[1][2] += a4.y * b4.z; acc[1][3] += a4.y * b4.w;
            acc[2][0] += a4.z * b4.x; acc[2][1] += a4.z * b4.y;
            acc[2][2] += a4.z * b4.z; acc[2][3] += a4.z * b4.w;
            acc[3][0] += a4.w * b4.x; acc[3][1] += a4.w * b4.y;
            acc[3][2] += a4.w * b4.z; acc[3][3] += a4.w * b4.w;
        }
    }
    const int col = bn + (tx << 2);
    float4 bv4 = *(const float4*)&bias[col];
#pragma unroll
    for (int i = 0; i < 4; ++i) {
        int row = bm + (ty << 2) + i;
        float4 o;
        o.x = acc[i][0] + bv4.x; o.y = acc[i][1] + bv4.y;
        o.z = acc[i][2] + bv4.z; o.w = acc[i][3] + bv4.w;
        *(float4*)&C[(size_t)row * N + col] = o;
    }
}

// ---------------------------------------------------------------------------
// Persistent LSTM scan. 32 blocks x 512 threads. Block j owns h slice
// [16j,16j+16). NEW partition: wave w owns h-indices {16j+2w, 16j+2w+1}
// (8 gate rows, full cell update stays inside the wave):
//   lane l: hi=l>>5 (which h), gate=(l>>3)&3 (i/f/g/o), s=l&7 (64-wide k seg)
// k-reduce = 3x shfl_xor, gate gather = 3x shfl_down, each wave publishes its
// own 2 h-atoms => ONE barrier/step, no part[] LDS, no wave-0 serial tail,
// activations parallel across all 8 waves.
// h_lds double-buffered by parity: a wave reaches its step-t+2 LDS write only
// after observing remote tags t+2, which transitively requires every wave of
// its own block to have published step t (data-dependent on its step-t reads).
// W_hh slice in VGPRs, chunk order rotated by s so the LDS reads hit 8
// distinct bank-quads (conflict-free) while w4[] stays compile-time-indexed.
// ---------------------------------------------------------------------------
__global__ __launch_bounds__(512, 2) void lstm_scan(const float* __restrict__ W_hh,
                                                    const float* __restrict__ xg,
                                                    float* __restrict__ hs,
                                                    uint64_t* __restrict__ hrec) {
    __shared__ __align__(16) float h_lds[2][512];
    const int tid = threadIdx.x;
    const int wv = tid >> 6;            // wave 0..7
    const int lane = tid & 63;
    const int j = blockIdx.x;
    const int hi = lane >> 5;           // 0/1: which of the wave's 2 h cols
    const int gate = (lane >> 3) & 3;   // 0:i 1:f 2:g 3:o
    const int s = lane & 7;             // k segment [64s, 64s+64)
    const int hidx = (j << 4) | (wv << 1) | hi;   // global h index 0..511
    const int rowg = (gate << 9) | hidx;          // gate row 0..2047

    // weights pre-rotated: w4[q] = row chunk ((q+s)&15) of my 64-wide segment
    float4 w4[16];
    {
        const float4* wp = (const float4*)(W_hh + (size_t)rowg * HDIM + (s << 6));
#pragma unroll
        for (int q = 0; q < 16; ++q) w4[q] = wp[(q + s) & 15];
    }

    const int fbase = s << 4;           // float4 base index of my segment
    const bool isg = (gate == 2);
    float c_reg = 0.f;                  // valid on gate==0 lanes (redundant per s)
    for (int t = 0; t < T_LEN; ++t) {
        // prefetch this step's x-gate contribution (independent of the spin)
        float xgv = xg[(size_t)t * G4 + rowg];

        // spin on my own 8B (h,tag) atom until tag == t
        uint64_t* src = hrec + ((t & 1) << 9) + tid;
        uint64_t u;
        int guard = 0;
        do {
            u = __hip_atomic_load(src, __ATOMIC_RELAXED, __HIP_MEMORY_SCOPE_AGENT);
        } while ((uint32_t)(u >> 32) != (uint32_t)t && ++guard < (1 << 18));
        float* hb = h_lds[t & 1];
        hb[tid] = __uint_as_float((uint32_t)u);
        __syncthreads();

        // matvec partial: my row, my 64-k segment (rotated chunk order)
        const float4* h4p = (const float4*)hb;
        float ac0 = 0.f, ac1 = 0.f, ac2 = 0.f, ac3 = 0.f;
#pragma unroll
        for (int q = 0; q < 16; q += 4) {
            float4 h0 = h4p[fbase | ((q + 0 + s) & 15)];
            float4 h1 = h4p[fbase | ((q + 1 + s) & 15)];
            float4 h2 = h4p[fbase | ((q + 2 + s) & 15)];
            float4 h3 = h4p[fbase | ((q + 3 + s) & 15)];
            ac0 += w4[q].x * h0.x + w4[q].y * h0.y + w4[q].z * h0.z + w4[q].w * h0.w;
            ac1 += w4[q + 1].x * h1.x + w4[q + 1].y * h1.y + w4[q + 1].z * h1.z + w4[q + 1].w * h1.w;
            ac2 += w4[q + 2].x * h2.x + w4[q + 2].y * h2.y + w4[q + 2].z * h2.z + w4[q + 2].w * h2.w;
            ac3 += w4[q + 3].x * h3.x + w4[q + 3].y * h3.y + w4[q + 3].z * h3.z + w4[q + 3].w * h3.w;
        }
        float v = (ac0 + ac1) + (ac2 + ac3);
        // k-reduce across the 8 s-lanes of my row (bits 0..2)
        v += __shfl_xor(v, 1);
        v += __shfl_xor(v, 2);
        v += __shfl_xor(v, 4);
        float g = v + xgv;

        // activation: sigmoid for i/f/o, tanh for g  (tanh(x)=2*sig(2x)-1)
        float y = isg ? (g + g) : g;
        float sg = 1.f / (1.f + __expf(-y));
        float a = isg ? (sg + sg - 1.f) : sg;

        // gather f/g/o onto gate==0 lanes (valid there; garbage elsewhere is unused)
        float fa = __shfl_down(a, 8);
        float ga = __shfl_down(a, 16);
        float oa = __shfl_down(a, 24);

        c_reg = fa * c_reg + a * ga;           // f*c + i*g  (gate==0 lanes)
        float e2 = __expf(-2.f * c_reg);
        float hv = oa * (2.f / (1.f + e2) - 1.f);   // o * tanh(c)

        if ((lane & 31) == 0) {                // gate==0, s==0 lane per h col
            uint64_t pu = ((uint64_t)(uint32_t)(t + 1) << 32) |
                          (uint64_t)__float_as_uint(hv);
            __hip_atomic_store(hrec + (((t + 1) & 1) << 9) + hidx, pu,
                               __ATOMIC_RELAXED, __HIP_MEMORY_SCOPE_AGENT);
            hs[(size_t)t * HDIM + hidx] = hv;
        }
    }
}

// ---------------------------------------------------------------------------
// heads: per block, 64 t-rows. inter tile + transposed head weights in LDS.
// action = clip(inter@fc1^T + b1), obj = clip(inter@fc2^T + b2)
// ---------------------------------------------------------------------------
__global__ __launch_bounds__(256) void heads_k(const float* __restrict__ inter,
                                               const float* __restrict__ fc1w,
                                               const float* __restrict__ fc1b,
                                               const float* __restrict__ fc2w,
                                               const float* __restrict__ fc2b,
                                               float* __restrict__ out) {
    __shared__ float it[64][128];   // 32 KB
    __shared__ float wt[128][56];   // 28 KB, transposed: [k][neuron]
    __shared__ float bl[56];
    const int tid = threadIdx.x;
    const int t0 = blockIdx.x << 6;
    for (int q = tid; q < 64 * 32; q += 256) {
        int r = q >> 5, c4 = q & 31;
        *(float4*)&it[r][c4 << 2] =
            *(const float4*)&inter[(size_t)(t0 + r) * 128 + (c4 << 2)];
    }
    for (int q = tid; q < 53 * 32; q += 256) {
        int r = q >> 5, c4 = q & 31;
        float4 v = (r < 16) ? ((const float4*)&fc1w[r * 128])[c4]
                            : ((const float4*)&fc2w[(r - 16) * 128])[c4];
        int k = c4 << 2;
        wt[k + 0][r] = v.x; wt[k + 1][r] = v.y; wt[k + 2][r] = v.z; wt[k + 3][r] = v.w;
    }
    if (tid < 53) bl[tid] = (tid < 16) ? fc1b[tid] : fc2b[tid - 16];
    __syncthreads();
    const int c = tid & 63, rg = tid >> 6;
    if (c < 53) {
        float b = bl[c];
        for (int rr = 0; rr < 16; ++rr) {
            int r = (rg << 4) + rr;
            float acc = b;
#pragma unroll 8
            for (int k = 0; k < 128; k += 4) {
                float4 iv = *(const float4*)&it[r][k];
                acc += iv.x * wt[k][c] + iv.y * wt[k + 1][c] +
                       iv.z * wt[k + 2][c] + iv.w * wt[k + 3][c];
            }
            acc = fminf(fmaxf(acc, 0.f), CLAMP_MAXV);
            int t = t0 + r;
            if (c < 16) out[(size_t)t * 16 + c] = acc;
            else        out[262144 + (size_t)t * 37 + (c - 16)] = acc;
        }
    }
}

// ---------------------------------------------------------------------------
extern "C" void kernel_launch(void* const* d_in, const int* in_sizes, int n_in,
                              void* d_out, int out_size, void* d_ws, size_t ws_size,
                              hipStream_t stream) {
    const float* x     = (const float*)d_in[0];
    const float* W_ih  = (const float*)d_in[1];
    const float* W_hh  = (const float*)d_in[2];
    const float* b_ih  = (const float*)d_in[3];
    const float* b_hh  = (const float*)d_in[4];
    const float* fc_w  = (const float*)d_in[5];
    const float* fc_b  = (const float*)d_in[6];
    const float* fc1_w = (const float*)d_in[7];
    const float* fc1_b = (const float*)d_in[8];
    const float* fc2_w = (const float*)d_in[9];
    const float* fc2_b = (const float*)d_in[10];

    if (ws_size < WS_NEED) return;   // visible failure rather than corruption

    char* ws = (char*)d_ws;
    float*    xg    = (float*)(ws + XG_OFF);
    float*    hs    = (float*)(ws + HS_OFF);
    float*    inter = (float*)(ws + INTER_OFF);
    uint64_t* hrec  = (uint64_t*)(ws + HREC_OFF);
    float*    bsum  = (float*)(ws + BSUM_OFF);
    float*    out   = (float*)d_out;

    hipLaunchKernelGGL(init_k, dim3(8), dim3(256), 0, stream, hrec, b_ih, b_hh, bsum);
    // x_gates = x @ W_ih^T + (b_ih + b_hh)   [16384 x 2048]
    hipLaunchKernelGGL(gemm_abt, dim3(256, 32), dim3(256), 0, stream,
                       x, W_ih, bsum, xg, 2048, 512);
    // sequential scan -> hs [16384 x 512]
    hipLaunchKernelGGL(lstm_scan, dim3(32), dim3(512), 0, stream, W_hh, xg, hs, hrec);
    // inter = hs @ fc_w^T + fc_b   [16384 x 128]
    hipLaunchKernelGGL(gemm_abt, dim3(256, 2), dim3(256), 0, stream,
                       hs, fc_w, fc_b, inter, 128, 512);
    // heads -> d_out
    hipLaunchKernelGGL(heads_k, dim3(256), dim3(256), 0, stream,
                       inter, fc1_w, fc1_b, fc2_w, fc2_b, out);
}

// Round 2
// 23123.235 us; speedup vs baseline: 1.6284x; 1.6284x over previous
//
#include <hip/hip_runtime.h>
#include <hip/hip_bf16.h>
#include <stdint.h>

#define T_LEN 16384
#define HDIM 512
#define G4 2048
#define CLAMP_MAXV 49688.0f

// workspace layout (bytes)
#define XG_OFF    0ull
#define HS_OFF    134217728ull   // 16384*2048*4
#define INTER_OFF 167772160ull   // + 16384*512*4
#define HREC_OFF  176160768ull   // + 16384*128*4
#define BSUM_OFF  176168960ull   // + 8192
#define WS_NEED   176177152ull

// ---------------------------------------------------------------------------
// init: zero the h-record (both parity buffers incl. tags), fold biases
// ---------------------------------------------------------------------------
__global__ __launch_bounds__(256) void init_k(uint64_t* __restrict__ hrec,
                                              const float* __restrict__ b_ih,
                                              const float* __restrict__ b_hh,
                                              float* __restrict__ bsum) {
    int i = blockIdx.x * 256 + threadIdx.x;   // grid 8x256 -> i in [0,2048)
    if (i < 1024) hrec[i] = 0ull;             // tag 0 == "h_{-1} ready", h = 0
    bsum[i] = b_ih[i] + b_hh[i];
}

// ---------------------------------------------------------------------------
// C[M,N] = A[M,K] @ B[N,K]^T + bias[N]   (both operands K-contiguous)
// 64x64 tile, 256 threads, 4x4 micro-tile, K-tile 16, LDS transposed + padded
// ---------------------------------------------------------------------------
__global__ __launch_bounds__(256) void gemm_abt(const float* __restrict__ A,
                                                const float* __restrict__ B,
                                                const float* __restrict__ bias,
                                                float* __restrict__ C,
                                                int N, int K) {
    __shared__ float As[16][68];
    __shared__ float Bs[16][68];
    const int tid = threadIdx.x;
    const int bm = blockIdx.x << 6, bn = blockIdx.y << 6;
    const int tx = tid & 15, ty = tid >> 4;
    const int lr = tid >> 2, lk = (tid & 3) << 2;
    float acc[4][4] = {};
    const float* Ap = A + (size_t)(bm + lr) * K + lk;
    const float* Bp = B + (size_t)(bn + lr) * K + lk;
    for (int kt = 0; kt < K; kt += 16) {
        float4 av = *(const float4*)(Ap + kt);
        float4 bv = *(const float4*)(Bp + kt);
        __syncthreads();
        As[lk + 0][lr] = av.x; As[lk + 1][lr] = av.y;
        As[lk + 2][lr] = av.z; As[lk + 3][lr] = av.w;
        Bs[lk + 0][lr] = bv.x; Bs[lk + 1][lr] = bv.y;
        Bs[lk + 2][lr] = bv.z; Bs[lk + 3][lr] = bv.w;
        __syncthreads();
#pragma unroll
        for (int kk = 0; kk < 16; ++kk) {
            float4 a4 = *(const float4*)&As[kk][ty << 2];
            float4 b4 = *(const float4*)&Bs[kk][tx << 2];
            acc[0][0] += a4.x * b4.x; acc[0][1] += a4.x * b4.y;
            acc[0][2] += a4.x * b4.z; acc[0][3] += a4.x * b4.w;
            acc[1][0] += a4.y * b4.x; acc[1][1] += a4.y * b4.y;
            acc[1][2] += a4.y * b4.z; acc[1][3] += a4.y * b4.w;
            acc[2][0] += a4.z * b4.x; acc[2][1] += a4.z * b4.y;
            acc[2][2] += a4.z * b4.z; acc[2][3] += a4.z * b4.w;
            acc[3][0] += a4.w * b4.x; acc[3][1] += a4.w * b4.y;
            acc[3][2] += a4.w * b4.z; acc[3][3] += a4.w * b4.w;
        }
    }
    const int col = bn + (tx << 2);
    float4 bv4 = *(const float4*)&bias[col];
#pragma unroll
    for (int i = 0; i < 4; ++i) {
        int row = bm + (ty << 2) + i;
        float4 o;
        o.x = acc[i][0] + bv4.x; o.y = acc[i][1] + bv4.y;
        o.z = acc[i][2] + bv4.z; o.w = acc[i][3] + bv4.w;
        *(float4*)&C[(size_t)row * N + col] = o;
    }
}

// ---------------------------------------------------------------------------
// Persistent LSTM scan. 32 blocks x 512 threads. Block j owns h slice
// [16j,16j+16) => 64 gate rows (i,f,g,o x 16). W_hh slice lives in VGPRs.
// Round-0 structure (single-wave contiguous publish, per-thread spin) with:
//  - barrier #1 removed: h_lds is wave-local (wave wv writes and reads only
//    its own 64-float segment; same-wave DS ops execute in order), part[]
//    double-buffered by t&1 so the one remaining barrier protects it.
//    Safety of part[t&1] reuse at t+2: a wave writes part[t&1] at t+2 only
//    after passing barrier(t+1), which wave 0 joins only after its tail(t)
//    reads of part[t&1] completed.
//  - 2-deep pipelined spin: keep 2 atomic loads in flight, test the older
//    one -> detection granularity ~ RT/2 instead of a full round trip.
//    No overshoot: slot parity (t&1) can only hold tags {t-2, t} while this
//    block still spins at t (producers can't publish t+2 before this block
//    publishes t+1, which is after these reads).
//  - wave 0 keeps its own seg-0 partial in a register (7 part reads, not 8);
//    waves 1-7 write part; atom publish issued before the hs store.
// Publish stays EXACTLY round-0: wave 0 lanes 0..15, 16 contiguous 8B atoms
// = one coalesced 128B transaction (round 1 proved scattering this costs
// ~+40%: WRITE_SIZE doubled from partial-line sectors, dur +44%).
// ---------------------------------------------------------------------------
__global__ __launch_bounds__(512, 2) void lstm_scan(const float* __restrict__ W_hh,
                                                    const float* __restrict__ xg,
                                                    float* __restrict__ hs,
                                                    uint64_t* __restrict__ hrec) {
    __shared__ __align__(16) float h_lds[512];
    __shared__ float part[2][512];
    const int tid = threadIdx.x;
    const int wv = tid >> 6;          // wave 0..7 = k segment
    const int lane = tid & 63;        // row within block's 64 gate rows
    const int j = blockIdx.x;
    // global gate row: 512*gate + 16*j + u   (gate = lane>>4, u = lane&15)
    const int rowg = ((lane >> 4) << 9) | (j << 4) | (lane & 15);

    float4 w4[16];
    {
        const float4* wp = (const float4*)(W_hh + (size_t)rowg * HDIM + (wv << 6));
#pragma unroll
        for (int q = 0; q < 16; ++q) w4[q] = wp[q];
    }

    float c_reg = 0.f;   // valid on wave 0, lanes 0..15
    for (int t = 0; t < T_LEN; ++t) {
        // prefetch this step's x-gate contribution (in flight during the spin)
        float xgv = 0.f;
        if (wv == 0) xgv = xg[(size_t)t * G4 + rowg];

        // 2-deep pipelined spin on my own 8B (h,tag) atom until tag == t
        uint64_t* src = hrec + ((t & 1) << 9) + tid;
        uint64_t a0 = __hip_atomic_load(src, __ATOMIC_RELAXED, __HIP_MEMORY_SCOPE_AGENT);
        uint64_t a1 = __hip_atomic_load(src, __ATOMIC_RELAXED, __HIP_MEMORY_SCOPE_AGENT);
        int guard = 0;
        while ((uint32_t)(a0 >> 32) != (uint32_t)t && ++guard < (1 << 18)) {
            a0 = a1;
            a1 = __hip_atomic_load(src, __ATOMIC_RELAXED, __HIP_MEMORY_SCOPE_AGENT);
        }
        h_lds[tid] = __uint_as_float((uint32_t)a0);
        __builtin_amdgcn_wave_barrier();   // pin ds_write before the reads

        // matvec: partial over my 64-k segment for my row (wave-local LDS,
        // uniform addresses -> broadcast reads, no barrier needed)
        float ac0 = 0.f, ac1 = 0.f, ac2 = 0.f, ac3 = 0.f;
        const float* hp = h_lds + (wv << 6);
#pragma unroll
        for (int q = 0; q < 16; q += 4) {
            float4 h0 = *(const float4*)(hp + (q << 2));
            float4 h1 = *(const float4*)(hp + ((q + 1) << 2));
            float4 h2 = *(const float4*)(hp + ((q + 2) << 2));
            float4 h3 = *(const float4*)(hp + ((q + 3) << 2));
            ac0 += w4[q].x * h0.x + w4[q].y * h0.y + w4[q].z * h0.z + w4[q].w * h0.w;
            ac1 += w4[q + 1].x * h1.x + w4[q + 1].y * h1.y + w4[q + 1].z * h1.z + w4[q + 1].w * h1.w;
            ac2 += w4[q + 2].x * h2.x + w4[q + 2].y * h2.y + w4[q + 2].z * h2.z + w4[q + 2].w * h2.w;
            ac3 += w4[q + 3].x * h3.x + w4[q + 3].y * h3.y + w4[q + 3].z * h3.z + w4[q + 3].w * h3.w;
        }
        float v = (ac0 + ac1) + (ac2 + ac3);
        if (wv) part[t & 1][tid] = v;
        __syncthreads();    // the ONE barrier per step

        if (wv == 0) {
            float g = xgv + v;        // own seg-0 partial stays in-register
            const float* pp = part[t & 1];
#pragma unroll
            for (int ww = 1; ww < 8; ++ww) g += pp[(ww << 6) | lane];
            // activation in parallel across all 64 rows:
            // rows 0..15 i(sig), 16..31 f(sig), 32..47 g(tanh), 48..63 o(sig)
            bool isg = (lane >= 32) && (lane < 48);
            float y = isg ? (g + g) : g;
            float s = 1.f / (1.f + __expf(-y));
            float a = isg ? (s + s - 1.f) : s;   // tanh(x) = 2*sig(2x)-1
            float fa = __shfl_down(a, 16);
            float ga = __shfl_down(a, 32);
            float oa = __shfl_down(a, 48);
            if (lane < 16) {
                c_reg = fa * c_reg + a * ga;
                float e2 = __expf(-2.f * c_reg);
                float hv = oa * (2.f / (1.f + e2) - 1.f);   // o * tanh(c)
                // publish FIRST (get the atom into flight), then record hs
                uint64_t pu = ((uint64_t)(uint32_t)(t + 1) << 32) |
                              (uint64_t)__float_as_uint(hv);
                __hip_atomic_store(hrec + (((t + 1) & 1) << 9) + (j << 4) + lane, pu,
                                   __ATOMIC_RELAXED, __HIP_MEMORY_SCOPE_AGENT);
                hs[(size_t)t * HDIM + (j << 4) + lane] = hv;
            }
        }
        // no barrier here: next step's h_lds writes are wave-local and next
        // part writes go to the other parity buffer, protected as derived above.
    }
}

// ---------------------------------------------------------------------------
// heads: per block, 64 t-rows. inter tile + transposed head weights in LDS.
// action = clip(inter@fc1^T + b1), obj = clip(inter@fc2^T + b2)
// ---------------------------------------------------------------------------
__global__ __launch_bounds__(256) void heads_k(const float* __restrict__ inter,
                                               const float* __restrict__ fc1w,
                                               const float* __restrict__ fc1b,
                                               const float* __restrict__ fc2w,
                                               const float* __restrict__ fc2b,
                                               float* __restrict__ out) {
    __shared__ float it[64][128];   // 32 KB
    __shared__ float wt[128][56];   // 28 KB, transposed: [k][neuron]
    __shared__ float bl[56];
    const int tid = threadIdx.x;
    const int t0 = blockIdx.x << 6;
    for (int q = tid; q < 64 * 32; q += 256) {
        int r = q >> 5, c4 = q & 31;
        *(float4*)&it[r][c4 << 2] =
            *(const float4*)&inter[(size_t)(t0 + r) * 128 + (c4 << 2)];
    }
    for (int q = tid; q < 53 * 32; q += 256) {
        int r = q >> 5, c4 = q & 31;
        float4 v = (r < 16) ? ((const float4*)&fc1w[r * 128])[c4]
                            : ((const float4*)&fc2w[(r - 16) * 128])[c4];
        int k = c4 << 2;
        wt[k + 0][r] = v.x; wt[k + 1][r] = v.y; wt[k + 2][r] = v.z; wt[k + 3][r] = v.w;
    }
    if (tid < 53) bl[tid] = (tid < 16) ? fc1b[tid] : fc2b[tid - 16];
    __syncthreads();
    const int c = tid & 63, rg = tid >> 6;
    if (c < 53) {
        float b = bl[c];
        for (int rr = 0; rr < 16; ++rr) {
            int r = (rg << 4) + rr;
            float acc = b;
#pragma unroll 8
            for (int k = 0; k < 128; k += 4) {
                float4 iv = *(const float4*)&it[r][k];
                acc += iv.x * wt[k][c] + iv.y * wt[k + 1][c] +
                       iv.z * wt[k + 2][c] + iv.w * wt[k + 3][c];
            }
            acc = fminf(fmaxf(acc, 0.f), CLAMP_MAXV);
            int t = t0 + r;
            if (c < 16) out[(size_t)t * 16 + c] = acc;
            else        out[262144 + (size_t)t * 37 + (c - 16)] = acc;
        }
    }
}

// ---------------------------------------------------------------------------
extern "C" void kernel_launch(void* const* d_in, const int* in_sizes, int n_in,
                              void* d_out, int out_size, void* d_ws, size_t ws_size,
                              hipStream_t stream) {
    const float* x     = (const float*)d_in[0];
    const float* W_ih  = (const float*)d_in[1];
    const float* W_hh  = (const float*)d_in[2];
    const float* b_ih  = (const float*)d_in[3];
    const float* b_hh  = (const float*)d_in[4];
    const float* fc_w  = (const float*)d_in[5];
    const float* fc_b  = (const float*)d_in[6];
    const float* fc1_w = (const float*)d_in[7];
    const float* fc1_b = (const float*)d_in[8];
    const float* fc2_w = (const float*)d_in[9];
    const float* fc2_b = (const float*)d_in[10];

    if (ws_size < WS_NEED) return;   // visible failure rather than corruption

    char* ws = (char*)d_ws;
    float*    xg    = (float*)(ws + XG_OFF);
    float*    hs    = (float*)(ws + HS_OFF);
    float*    inter = (float*)(ws + INTER_OFF);
    uint64_t* hrec  = (uint64_t*)(ws + HREC_OFF);
    float*    bsum  = (float*)(ws + BSUM_OFF);
    float*    out   = (float*)d_out;

    hipLaunchKernelGGL(init_k, dim3(8), dim3(256), 0, stream, hrec, b_ih, b_hh, bsum);
    // x_gates = x @ W_ih^T + (b_ih + b_hh)   [16384 x 2048]
    hipLaunchKernelGGL(gemm_abt, dim3(256, 32), dim3(256), 0, stream,
                       x, W_ih, bsum, xg, 2048, 512);
    // sequential scan -> hs [16384 x 512]
    hipLaunchKernelGGL(lstm_scan, dim3(32), dim3(512), 0, stream, W_hh, xg, hs, hrec);
    // inter = hs @ fc_w^T + fc_b   [16384 x 128]
    hipLaunchKernelGGL(gemm_abt, dim3(256, 2), dim3(256), 0, stream,
                       hs, fc_w, fc_b, inter, 128, 512);
    // heads -> d_out
    hipLaunchKernelGGL(heads_k, dim3(256), dim3(256), 0, stream,
                       inter, fc1_w, fc1_b, fc2_w, fc2_b, out);
}